// Round 1
// baseline (774.961 us; speedup 1.0000x reference)
//
#include <hip/hip_runtime.h>

#define N_NODES 100000
#define N_EDGES 3200000
#define N_GRAPHS 1024
#define F_IN 4
#define H 16

// ---------------- kernels ----------------

__global__ void k_zero(float* __restrict__ p, int n) {
    int i = blockIdx.x * blockDim.x + threadIdx.x;
    if (i < n) p[i] = 0.0f;
}

// count edges per dst node
__global__ void k_deg(const int* __restrict__ dst, float* __restrict__ deg, int e) {
    int i = blockIdx.x * blockDim.x + threadIdx.x;
    if (i < e) atomicAdd(&deg[dst[i]], 1.0f);
}

// dinv = rsqrt(deg + 1)  (+1 = self loop)
__global__ void k_dinv(const float* __restrict__ deg, float* __restrict__ dinv, int n) {
    int i = blockIdx.x * blockDim.x + threadIdx.x;
    if (i < n) dinv[i] = rsqrtf(deg[i] + 1.0f);
}

// dense matmul: out[i, 0..15] = in[i, :] @ W   (no bias)
template <int FI>
__global__ void k_matmul(const float* __restrict__ in, const float* __restrict__ W,
                         float* __restrict__ out, int n) {
    __shared__ float sW[FI * H];
    for (int t = threadIdx.x; t < FI * H; t += blockDim.x) sW[t] = W[t];
    __syncthreads();
    int i = blockIdx.x * blockDim.x + threadIdx.x;
    if (i >= n) return;
    float xin[FI];
#pragma unroll
    for (int j = 0; j < FI; j++) xin[j] = in[i * FI + j];
#pragma unroll
    for (int o = 0; o < H; o++) {
        float acc = 0.0f;
#pragma unroll
        for (int j = 0; j < FI; j++) acc += xin[j] * sW[j * H + o];
        out[i * H + o] = acc;
    }
}

// out[i,k] = bias[k] + dinv[i]^2 * tmp[i,k]   (self-loop term + bias)
__global__ void k_init_out(const float* __restrict__ tmp, const float* __restrict__ dinv,
                           const float* __restrict__ b, float* __restrict__ out, int nh) {
    int t = blockIdx.x * blockDim.x + threadIdx.x;
    if (t >= nh) return;
    int i = t >> 4;
    int k = t & 15;
    float dv = dinv[i];
    out[t] = b[k] + dv * dv * tmp[t];
}

// edge scatter: out[dst,k] += dinv[src]*dinv[dst] * tmp[src,k]
__global__ void k_scatter(const float* __restrict__ tmp, const float* __restrict__ dinv,
                          const int* __restrict__ src, const int* __restrict__ dst,
                          float* __restrict__ out, long long tot) {
    long long t = (long long)blockIdx.x * blockDim.x + threadIdx.x;
    if (t >= tot) return;
    int e = (int)(t >> 4);
    int k = (int)(t & 15);
    int s = src[e];
    int d = dst[e];
    float w = dinv[s] * dinv[d];
    atomicAdd(&out[d * H + k], w * tmp[s * H + k]);
}

__global__ void k_relu(float* __restrict__ p, int n) {
    int i = blockIdx.x * blockDim.x + threadIdx.x;
    if (i < n) p[i] = fmaxf(p[i], 0.0f);
}

// pool: g[batch[i], k] += h[i, k]
__global__ void k_pool(const float* __restrict__ h, const int* __restrict__ batch,
                       float* __restrict__ g, int nh) {
    int t = blockIdx.x * blockDim.x + threadIdx.x;
    if (t >= nh) return;
    int i = t >> 4;
    int k = t & 15;
    atomicAdd(&g[batch[i] * H + k], h[t]);
}

// final MLP: one thread per graph
__global__ void k_mlp(const float* __restrict__ g, const float* __restrict__ y,
                      const float* __restrict__ fcW1, const float* __restrict__ fcb1,
                      const float* __restrict__ fcW2, const float* __restrict__ fcb2,
                      const float* __restrict__ fcW3, const float* __restrict__ fcb3,
                      float* __restrict__ out, int ngraph) {
    int i = blockIdx.x * blockDim.x + threadIdx.x;
    if (i >= ngraph) return;
    float in[H + 4];
#pragma unroll
    for (int k = 0; k < H; k++) in[k] = g[i * H + k];
#pragma unroll
    for (int k = 0; k < 4; k++) in[H + k] = y[i * 4 + k];
    float z1[H];
#pragma unroll
    for (int o = 0; o < H; o++) {
        float a = fcb1[o];
#pragma unroll
        for (int j = 0; j < H + 4; j++) a += in[j] * fcW1[j * H + o];
        z1[o] = fmaxf(a, 0.0f);
    }
    float z2[H];
#pragma unroll
    for (int o = 0; o < H; o++) {
        float a = fcb2[o];
#pragma unroll
        for (int j = 0; j < H; j++) a += z1[j] * fcW2[j * H + o];
        z2[o] = fmaxf(a, 0.0f);
    }
    float a = fcb3[0];
#pragma unroll
    for (int j = 0; j < H; j++) a += z2[j] * fcW3[j];
    out[i] = a;
}

// ---------------- launch ----------------

extern "C" void kernel_launch(void* const* d_in, const int* in_sizes, int n_in,
                              void* d_out, int out_size, void* d_ws, size_t ws_size,
                              hipStream_t stream) {
    const float* x    = (const float*)d_in[0];
    const int*   ei   = (const int*)d_in[1];   // [2, E]: src then dst
    const float* y    = (const float*)d_in[2];
    const int*   bat  = (const int*)d_in[3];
    const float* W1   = (const float*)d_in[4];
    const float* b1   = (const float*)d_in[5];
    const float* W2   = (const float*)d_in[6];
    const float* b2   = (const float*)d_in[7];
    const float* W3   = (const float*)d_in[8];
    const float* b3   = (const float*)d_in[9];
    const float* fcW1 = (const float*)d_in[10];
    const float* fcb1 = (const float*)d_in[11];
    const float* fcW2 = (const float*)d_in[12];
    const float* fcb2 = (const float*)d_in[13];
    const float* fcW3 = (const float*)d_in[14];
    const float* fcb3 = (const float*)d_in[15];
    float* out = (float*)d_out;

    const int* src = ei;
    const int* dst = ei + N_EDGES;

    // workspace layout (floats)
    float* ws   = (float*)d_ws;
    float* deg  = ws;                         // N
    float* dinv = deg + N_NODES;              // N
    float* bufA = dinv + N_NODES;             // N*H
    float* bufB = bufA + (size_t)N_NODES * H; // N*H
    float* g    = bufB + (size_t)N_NODES * H; // G*H

    const int B = 256;
    const int NH = N_NODES * H;
    const long long E16 = (long long)N_EDGES * H;
    const int gN   = (N_NODES + B - 1) / B;
    const int gNH  = (NH + B - 1) / B;
    const int gE   = (N_EDGES + B - 1) / B;
    const int gE16 = (int)((E16 + B - 1) / B);
    const int GH = N_GRAPHS * H;
    const int gGH = (GH + B - 1) / B;

    // degrees + dinv
    k_zero<<<gN, B, 0, stream>>>(deg, N_NODES);
    k_deg<<<gE, B, 0, stream>>>(dst, deg, N_EDGES);
    k_dinv<<<gN, B, 0, stream>>>(deg, dinv, N_NODES);

    // layer 1: x (N x 4) -> bufB (N x 16)
    k_matmul<F_IN><<<gN, B, 0, stream>>>(x, W1, bufA, N_NODES);
    k_init_out<<<gNH, B, 0, stream>>>(bufA, dinv, b1, bufB, NH);
    k_scatter<<<gE16, B, 0, stream>>>(bufA, dinv, src, dst, bufB, E16);
    k_relu<<<gNH, B, 0, stream>>>(bufB, NH);

    // layer 2: bufB -> bufB
    k_matmul<H><<<gN, B, 0, stream>>>(bufB, W2, bufA, N_NODES);
    k_init_out<<<gNH, B, 0, stream>>>(bufA, dinv, b2, bufB, NH);
    k_scatter<<<gE16, B, 0, stream>>>(bufA, dinv, src, dst, bufB, E16);
    k_relu<<<gNH, B, 0, stream>>>(bufB, NH);

    // layer 3: bufB -> bufB
    k_matmul<H><<<gN, B, 0, stream>>>(bufB, W3, bufA, N_NODES);
    k_init_out<<<gNH, B, 0, stream>>>(bufA, dinv, b3, bufB, NH);
    k_scatter<<<gE16, B, 0, stream>>>(bufA, dinv, src, dst, bufB, E16);
    k_relu<<<gNH, B, 0, stream>>>(bufB, NH);

    // pool
    k_zero<<<gGH, B, 0, stream>>>(g, GH);
    k_pool<<<gNH, B, 0, stream>>>(bufB, bat, g, NH);

    // final MLP
    k_mlp<<<(N_GRAPHS + B - 1) / B, B, 0, stream>>>(g, y, fcW1, fcb1, fcW2, fcb2,
                                                    fcW3, fcb3, out, N_GRAPHS);
}

// Round 2
// 757.727 us; speedup vs baseline: 1.0227x; 1.0227x over previous
//
#include <hip/hip_runtime.h>

#define N_NODES 100000
#define N_EDGES 3200000
#define N_GRAPHS 1024
#define F_IN 4
#define H 16
#define SCAN_CHUNK 1024
#define N_CHUNKS ((N_NODES + SCAN_CHUNK - 1) / SCAN_CHUNK)   // 98

// ---------------- common small kernels ----------------

__global__ void k_zero_f(float* __restrict__ p, int n) {
    int i = blockIdx.x * blockDim.x + threadIdx.x;
    if (i < n) p[i] = 0.0f;
}

__global__ void k_zero_i(int* __restrict__ p, int n) {
    int i = blockIdx.x * blockDim.x + threadIdx.x;
    if (i < n) p[i] = 0;
}

// count edges per dst node (int)
__global__ void k_deg(const int* __restrict__ dst, int* __restrict__ deg, int e) {
    int i = blockIdx.x * blockDim.x + threadIdx.x;
    if (i < e) atomicAdd(&deg[dst[i]], 1);
}

// dinv = rsqrt(deg + 1)  (+1 = self loop)
__global__ void k_dinv(const int* __restrict__ deg, float* __restrict__ dinv, int n) {
    int i = blockIdx.x * blockDim.x + threadIdx.x;
    if (i < n) dinv[i] = rsqrtf((float)deg[i] + 1.0f);
}

// ---------------- scan (exclusive prefix sum of deg -> cursor) ----------------

__global__ void k_scanA(const int* __restrict__ deg, int* __restrict__ cursor,
                        int* __restrict__ sums, int n) {
    __shared__ int sh[SCAN_CHUNK];
    int t = threadIdx.x;
    int i = blockIdx.x * SCAN_CHUNK + t;
    int v = (i < n) ? deg[i] : 0;
    sh[t] = v;
    __syncthreads();
    for (int off = 1; off < SCAN_CHUNK; off <<= 1) {
        int x = (t >= off) ? sh[t - off] : 0;
        __syncthreads();
        sh[t] += x;
        __syncthreads();
    }
    if (i < n) cursor[i] = sh[t] - v;  // exclusive
    if (t == SCAN_CHUNK - 1) sums[blockIdx.x] = sh[t];
}

__global__ void k_scanB(int* __restrict__ sums, int nb) {
    __shared__ int sh[128];
    int t = threadIdx.x;
    int v = (t < nb) ? sums[t] : 0;
    sh[t] = v;
    __syncthreads();
    for (int off = 1; off < 128; off <<= 1) {
        int x = (t >= off) ? sh[t - off] : 0;
        __syncthreads();
        sh[t] += x;
        __syncthreads();
    }
    if (t < nb) sums[t] = sh[t] - v;  // exclusive
}

__global__ void k_scanC(int* __restrict__ cursor, const int* __restrict__ sums, int n) {
    int i = blockIdx.x * blockDim.x + threadIdx.x;
    if (i < n) cursor[i] += sums[i >> 10];
}

// counting-sort placement: after this, cursor[i] == end offset of node i
__global__ void k_build(const int* __restrict__ src, const int* __restrict__ dst,
                        int* __restrict__ cursor, int* __restrict__ csr, int e) {
    int i = blockIdx.x * blockDim.x + threadIdx.x;
    if (i < e) {
        int d = dst[i];
        int pos = atomicAdd(&cursor[d], 1);
        csr[pos] = src[i];
    }
}

// ---------------- dense matmul: out[i, 0..15] = in[i, :] @ W ----------------

template <int FI>
__global__ void k_matmul(const float* __restrict__ in, const float* __restrict__ W,
                         float* __restrict__ out, int n) {
    __shared__ float sW[FI * H];
    for (int t = threadIdx.x; t < FI * H; t += blockDim.x) sW[t] = W[t];
    __syncthreads();
    int i = blockIdx.x * blockDim.x + threadIdx.x;
    if (i >= n) return;
    float xin[FI];
#pragma unroll
    for (int j = 0; j < FI; j++) xin[j] = in[i * FI + j];
#pragma unroll
    for (int o = 0; o < H; o++) {
        float acc = 0.0f;
#pragma unroll
        for (int j = 0; j < FI; j++) acc += xin[j] * sW[j * H + o];
        out[i * H + o] = acc;
    }
}

// ---------------- CSR gather: fused self-loop + bias + relu (+ optional pool) ----------------
// 16 threads per node, lane k owns feature k.
template <bool POOL>
__global__ void k_gather(const float* __restrict__ tmp, const float* __restrict__ dinv,
                         const int* __restrict__ csr, const int* __restrict__ cursor,
                         const float* __restrict__ bias, float* __restrict__ out,
                         const int* __restrict__ batch, float* __restrict__ g, int n) {
    int i = blockIdx.x * 16 + (threadIdx.x >> 4);
    int k = threadIdx.x & 15;
    if (i >= n) return;
    float di = dinv[i];
    float acc = bias[k] + di * di * tmp[i * H + k];
    int start = (i == 0) ? 0 : cursor[i - 1];
    int end = cursor[i];
    for (int j = start; j < end; ++j) {
        int s = csr[j];
        acc = fmaf(di * dinv[s], tmp[s * H + k], acc);
    }
    float v = fmaxf(acc, 0.0f);
    if (POOL) {
        atomicAdd(&g[batch[i] * H + k], v);
    } else {
        out[i * H + k] = v;
    }
}

// ---------------- fallback (round-1) kernels ----------------

__global__ void k_init_out(const float* __restrict__ tmp, const float* __restrict__ dinv,
                           const float* __restrict__ b, float* __restrict__ out, int nh) {
    int t = blockIdx.x * blockDim.x + threadIdx.x;
    if (t >= nh) return;
    int i = t >> 4;
    int k = t & 15;
    float dv = dinv[i];
    out[t] = b[k] + dv * dv * tmp[t];
}

__global__ void k_scatter(const float* __restrict__ tmp, const float* __restrict__ dinv,
                          const int* __restrict__ src, const int* __restrict__ dst,
                          float* __restrict__ out, long long tot) {
    long long t = (long long)blockIdx.x * blockDim.x + threadIdx.x;
    if (t >= tot) return;
    int e = (int)(t >> 4);
    int k = (int)(t & 15);
    int s = src[e];
    int d = dst[e];
    float w = dinv[s] * dinv[d];
    atomicAdd(&out[d * H + k], w * tmp[s * H + k]);
}

__global__ void k_relu(float* __restrict__ p, int n) {
    int i = blockIdx.x * blockDim.x + threadIdx.x;
    if (i < n) p[i] = fmaxf(p[i], 0.0f);
}

__global__ void k_pool(const float* __restrict__ h, const int* __restrict__ batch,
                       float* __restrict__ g, int nh) {
    int t = blockIdx.x * blockDim.x + threadIdx.x;
    if (t >= nh) return;
    int i = t >> 4;
    int k = t & 15;
    atomicAdd(&g[batch[i] * H + k], h[t]);
}

// ---------------- final MLP ----------------

__global__ void k_mlp(const float* __restrict__ g, const float* __restrict__ y,
                      const float* __restrict__ fcW1, const float* __restrict__ fcb1,
                      const float* __restrict__ fcW2, const float* __restrict__ fcb2,
                      const float* __restrict__ fcW3, const float* __restrict__ fcb3,
                      float* __restrict__ out, int ngraph) {
    int i = blockIdx.x * blockDim.x + threadIdx.x;
    if (i >= ngraph) return;
    float in[H + 4];
#pragma unroll
    for (int k = 0; k < H; k++) in[k] = g[i * H + k];
#pragma unroll
    for (int k = 0; k < 4; k++) in[H + k] = y[i * 4 + k];
    float z1[H];
#pragma unroll
    for (int o = 0; o < H; o++) {
        float a = fcb1[o];
#pragma unroll
        for (int j = 0; j < H + 4; j++) a += in[j] * fcW1[j * H + o];
        z1[o] = fmaxf(a, 0.0f);
    }
    float z2[H];
#pragma unroll
    for (int o = 0; o < H; o++) {
        float a = fcb2[o];
#pragma unroll
        for (int j = 0; j < H; j++) a += z1[j] * fcW2[j * H + o];
        z2[o] = fmaxf(a, 0.0f);
    }
    float a = fcb3[0];
#pragma unroll
    for (int j = 0; j < H; j++) a += z2[j] * fcW3[j];
    out[i] = a;
}

// ---------------- launch ----------------

extern "C" void kernel_launch(void* const* d_in, const int* in_sizes, int n_in,
                              void* d_out, int out_size, void* d_ws, size_t ws_size,
                              hipStream_t stream) {
    const float* x    = (const float*)d_in[0];
    const int*   ei   = (const int*)d_in[1];   // [2, E]: src then dst
    const float* y    = (const float*)d_in[2];
    const int*   bat  = (const int*)d_in[3];
    const float* W1   = (const float*)d_in[4];
    const float* b1   = (const float*)d_in[5];
    const float* W2   = (const float*)d_in[6];
    const float* b2   = (const float*)d_in[7];
    const float* W3   = (const float*)d_in[8];
    const float* b3   = (const float*)d_in[9];
    const float* fcW1 = (const float*)d_in[10];
    const float* fcb1 = (const float*)d_in[11];
    const float* fcW2 = (const float*)d_in[12];
    const float* fcb2 = (const float*)d_in[13];
    const float* fcW3 = (const float*)d_in[14];
    const float* fcb3 = (const float*)d_in[15];
    float* out = (float*)d_out;

    const int* src = ei;
    const int* dst = ei + N_EDGES;

    const int B = 256;
    const int NH = N_NODES * H;
    const int GH = N_GRAPHS * H;
    const int gN  = (N_NODES + B - 1) / B;
    const int gNH = (NH + B - 1) / B;
    const int gE  = (N_EDGES + B - 1) / B;
    const int gGH = (GH + B - 1) / B;
    const int gGather = (N_NODES + 15) / 16;

    // ---- workspace layout (CSR path) ----
    char* w = (char*)d_ws;
    size_t need = 0;
    int*   deg    = (int*)(w + need);   need += (size_t)N_NODES * 4;
    int*   cursor = (int*)(w + need);   need += (size_t)N_NODES * 4;
    float* dinv   = (float*)(w + need); need += (size_t)N_NODES * 4;
    int*   sums   = (int*)(w + need);   need += 128 * 4;
    int*   csr    = (int*)(w + need);   need += (size_t)N_EDGES * 4;
    float* bufA   = (float*)(w + need); need += (size_t)NH * 4;
    float* bufB   = (float*)(w + need); need += (size_t)NH * 4;
    float* g      = (float*)(w + need); need += (size_t)GH * 4;

    if (ws_size >= need) {
        // ---- CSR path ----
        k_zero_i<<<gN, B, 0, stream>>>(deg, N_NODES);
        k_deg<<<gE, B, 0, stream>>>(dst, deg, N_EDGES);
        k_dinv<<<gN, B, 0, stream>>>(deg, dinv, N_NODES);

        k_scanA<<<N_CHUNKS, SCAN_CHUNK, 0, stream>>>(deg, cursor, sums, N_NODES);
        k_scanB<<<1, 128, 0, stream>>>(sums, N_CHUNKS);
        k_scanC<<<gN, B, 0, stream>>>(cursor, sums, N_NODES);
        k_build<<<gE, B, 0, stream>>>(src, dst, cursor, csr, N_EDGES);

        // layer 1
        k_matmul<F_IN><<<gN, B, 0, stream>>>(x, W1, bufA, N_NODES);
        k_gather<false><<<gGather, B, 0, stream>>>(bufA, dinv, csr, cursor, b1, bufB,
                                                   nullptr, nullptr, N_NODES);
        // layer 2
        k_matmul<H><<<gN, B, 0, stream>>>(bufB, W2, bufA, N_NODES);
        k_gather<false><<<gGather, B, 0, stream>>>(bufA, dinv, csr, cursor, b2, bufB,
                                                   nullptr, nullptr, N_NODES);
        // layer 3 + fused pool
        k_matmul<H><<<gN, B, 0, stream>>>(bufB, W3, bufA, N_NODES);
        k_zero_f<<<gGH, B, 0, stream>>>(g, GH);
        k_gather<true><<<gGather, B, 0, stream>>>(bufA, dinv, csr, cursor, b3, nullptr,
                                                  bat, g, N_NODES);

        k_mlp<<<(N_GRAPHS + B - 1) / B, B, 0, stream>>>(g, y, fcW1, fcb1, fcW2, fcb2,
                                                        fcW3, fcb3, out, N_GRAPHS);
    } else {
        // ---- fallback: round-1 atomic path (smaller ws footprint) ----
        float* fdeg  = (float*)d_ws;                      // N
        float* fdinv = fdeg + N_NODES;                    // N
        float* fA    = fdinv + N_NODES;                   // N*H
        float* fB    = fA + (size_t)NH;                   // N*H
        float* fg    = fB + (size_t)NH;                   // G*H
        const long long E16 = (long long)N_EDGES * H;
        const int gE16 = (int)((E16 + B - 1) / B);

        k_zero_f<<<gN, B, 0, stream>>>(fdeg, N_NODES);
        // reuse int deg kernel semantics via float atomics
        // (simple: count with float adds)
        // k_deg expects int*, so do a tiny dedicated pass:
        // count via atomicAdd on float
        {
            // inline float-degree kernel via lambda is not possible; use k_pool-style trick:
            // simplest: launch k_deg on reinterpreted buffer is wrong; do scatter of ones:
        }
        // float degree count
        // (defined below as a separate kernel)
        extern __global__ void k_degf(const int*, float*, int);
        k_degf<<<gE, B, 0, stream>>>(dst, fdeg, N_EDGES);
        {
            // dinv
            extern __global__ void k_dinvf(const float*, float*, int);
            k_dinvf<<<gN, B, 0, stream>>>(fdeg, fdinv, N_NODES);
        }

        k_matmul<F_IN><<<gN, B, 0, stream>>>(x, W1, fA, N_NODES);
        k_init_out<<<gNH, B, 0, stream>>>(fA, fdinv, b1, fB, NH);
        k_scatter<<<gE16, B, 0, stream>>>(fA, fdinv, src, dst, fB, E16);
        k_relu<<<gNH, B, 0, stream>>>(fB, NH);

        k_matmul<H><<<gN, B, 0, stream>>>(fB, W2, fA, N_NODES);
        k_init_out<<<gNH, B, 0, stream>>>(fA, fdinv, b2, fB, NH);
        k_scatter<<<gE16, B, 0, stream>>>(fA, fdinv, src, dst, fB, E16);
        k_relu<<<gNH, B, 0, stream>>>(fB, NH);

        k_matmul<H><<<gN, B, 0, stream>>>(fB, W3, fA, N_NODES);
        k_init_out<<<gNH, B, 0, stream>>>(fA, fdinv, b3, fB, NH);
        k_scatter<<<gE16, B, 0, stream>>>(fA, fdinv, src, dst, fB, E16);
        k_relu<<<gNH, B, 0, stream>>>(fB, NH);

        k_zero_f<<<gGH, B, 0, stream>>>(fg, GH);
        k_pool<<<gNH, B, 0, stream>>>(fB, bat, fg, NH);
        k_mlp<<<(N_GRAPHS + B - 1) / B, B, 0, stream>>>(fg, y, fcW1, fcb1, fcW2, fcb2,
                                                        fcW3, fcb3, out, N_GRAPHS);
    }
}

// fallback helper kernels
__global__ void k_degf(const int* __restrict__ dst, float* __restrict__ deg, int e) {
    int i = blockIdx.x * blockDim.x + threadIdx.x;
    if (i < e) atomicAdd(&deg[dst[i]], 1.0f);
}

__global__ void k_dinvf(const float* __restrict__ deg, float* __restrict__ dinv, int n) {
    int i = blockIdx.x * blockDim.x + threadIdx.x;
    if (i < n) dinv[i] = rsqrtf(deg[i] + 1.0f);
}

// Round 3
// 340.349 us; speedup vs baseline: 2.2770x; 2.2263x over previous
//
#include <hip/hip_runtime.h>

#define N_NODES 100000
#define N_EDGES 3200000
#define N_GRAPHS 1024
#define F_IN 4
#define H 16

#define NB 1024      // dst buckets
#define NPB 98       // nodes per bucket (98*1021 >= 100000)
#define CAP 4096     // per-bucket LDS fast-path capacity (mean 3125, sigma 56)
#define CHUNK 4096   // edges per block in k_bucket
#define EPT 16       // edges per thread

#define SCAN_CHUNK 1024
#define N_CHUNKS ((N_NODES + SCAN_CHUNK - 1) / SCAN_CHUNK)   // 98 (fallback path)

// ---------------- tiny utility kernels ----------------

__global__ void k_zero_f(float* __restrict__ p, int n) {
    int i = blockIdx.x * blockDim.x + threadIdx.x;
    if (i < n) p[i] = 0.0f;
}

__global__ void k_zero_i(int* __restrict__ p, int n) {
    int i = blockIdx.x * blockDim.x + threadIdx.x;
    if (i < n) p[i] = 0;
}

// ---------------- fast CSR build (bucketed) ----------------

// per-block LDS histogram of dst buckets, flushed with global atomics
__global__ void k_hist(const int* __restrict__ dst, int* __restrict__ bucketCnt, int e) {
    __shared__ int h[NB];
    for (int t = threadIdx.x; t < NB; t += blockDim.x) h[t] = 0;
    __syncthreads();
    for (int i = blockIdx.x * blockDim.x + threadIdx.x; i < e; i += gridDim.x * blockDim.x)
        atomicAdd(&h[dst[i] / NPB], 1);
    __syncthreads();
    for (int t = threadIdx.x; t < NB; t += blockDim.x) {
        int c = h[t];
        if (c) atomicAdd(&bucketCnt[t], c);
    }
}

// exclusive scan of the 1024 bucket counts; one block of 1024 threads
__global__ void k_scan_buckets(const int* __restrict__ bucketCnt,
                               int* __restrict__ bucketBase,
                               int* __restrict__ bucketCursor) {
    __shared__ int sh[NB];
    int t = threadIdx.x;
    int v = bucketCnt[t];
    sh[t] = v;
    __syncthreads();
    for (int off = 1; off < NB; off <<= 1) {
        int x = (t >= off) ? sh[t - off] : 0;
        __syncthreads();
        sh[t] += x;
        __syncthreads();
    }
    int base = sh[t] - v;
    bucketBase[t] = base;
    bucketCursor[t] = base;
}

// distribute edges into exact-size bucket regions; writes grouped into
// contiguous per-block runs so L2 can merge them before eviction.
// payload packed: (local_dst << 20) | src   (src < 2^20, local_dst < 98)
__global__ void k_bucket(const int* __restrict__ src, const int* __restrict__ dst,
                         int* __restrict__ bucketCursor, int* __restrict__ ebuf, int e) {
    __shared__ int cnt[NB];
    __shared__ int lbase[NB];
    int t = threadIdx.x;
    for (int q = t; q < NB; q += blockDim.x) cnt[q] = 0;
    __syncthreads();
    int e0 = blockIdx.x * CHUNK;
    int vq[EPT], bq[EPT], rq[EPT];
#pragma unroll
    for (int q = 0; q < EPT; ++q) {
        int ei = e0 + t + q * 256;
        bq[q] = -1;
        if (ei < e) {
            int s = src[ei];
            int d = dst[ei];
            int b = d / NPB;
            int l = d - b * NPB;
            vq[q] = s | (l << 20);
            bq[q] = b;
            rq[q] = atomicAdd(&cnt[b], 1);
        }
    }
    __syncthreads();
    for (int q = t; q < NB; q += blockDim.x) {
        int c = cnt[q];
        lbase[q] = c ? atomicAdd(&bucketCursor[q], c) : 0;
    }
    __syncthreads();
#pragma unroll
    for (int q = 0; q < EPT; ++q)
        if (bq[q] >= 0) ebuf[lbase[bq[q]] + rq[q]] = vq[q];
}

// one block per bucket: group by exact node, emit coalesced CSR + cursor + dinv
__global__ void k_csrify(const int* __restrict__ ebuf, const int* __restrict__ bucketBase,
                         const int* __restrict__ bucketCnt, int* __restrict__ csr,
                         int* __restrict__ cursor, float* __restrict__ dinv) {
    __shared__ int cnt[128];
    __shared__ int sc[128];
    __shared__ int st[128];
    __shared__ int lcsr[CAP];
    int t = threadIdx.x;
    int b = blockIdx.x;
    int base = bucketBase[b];
    int m = bucketCnt[b];
    int nbase = b * NPB;
    if (t < 128) cnt[t] = 0;
    __syncthreads();

    if (m <= CAP) {
        int vs[EPT], ls[EPT], rk[EPT];
#pragma unroll
        for (int q = 0; q < EPT; ++q) {
            int idx = t + q * 256;
            if (idx < m) {
                int v = ebuf[base + idx];
                int s = v & 0xFFFFF;
                int l = v >> 20;
                vs[q] = s;
                ls[q] = l;
                rk[q] = atomicAdd(&cnt[l], 1);
            }
        }
        __syncthreads();
        int v0 = (t < 128) ? cnt[t] : 0;
        if (t < 128) sc[t] = v0;
        __syncthreads();
        for (int off = 1; off < 128; off <<= 1) {
            int x = (t < 128 && t >= off) ? sc[t - off] : 0;
            __syncthreads();
            if (t < 128) sc[t] += x;
            __syncthreads();
        }
        if (t < 128) st[t] = sc[t] - v0;
        __syncthreads();
        if (t < NPB) {
            int i = nbase + t;
            if (i < N_NODES) {
                dinv[i] = rsqrtf((float)cnt[t] + 1.0f);
                cursor[i] = base + st[t] + cnt[t];
            }
        }
#pragma unroll
        for (int q = 0; q < EPT; ++q) {
            int idx = t + q * 256;
            if (idx < m) lcsr[st[ls[q]] + rk[q]] = vs[q];
        }
        __syncthreads();
        for (int idx = t; idx < m; idx += 256) csr[base + idx] = lcsr[idx];
    } else {
        // capacity-proof slow path (never expected for this input)
        for (int idx = t; idx < m; idx += 256) {
            int v = ebuf[base + idx];
            atomicAdd(&cnt[v >> 20], 1);
        }
        __syncthreads();
        int v0 = (t < 128) ? cnt[t] : 0;
        if (t < 128) sc[t] = v0;
        __syncthreads();
        for (int off = 1; off < 128; off <<= 1) {
            int x = (t < 128 && t >= off) ? sc[t - off] : 0;
            __syncthreads();
            if (t < 128) sc[t] += x;
            __syncthreads();
        }
        if (t < 128) st[t] = sc[t] - v0;
        if (t < 128) lcsr[t] = 0;  // reuse as cnt2
        __syncthreads();
        if (t < NPB) {
            int i = nbase + t;
            if (i < N_NODES) {
                dinv[i] = rsqrtf((float)cnt[t] + 1.0f);
                cursor[i] = base + st[t] + cnt[t];
            }
        }
        for (int idx = t; idx < m; idx += 256) {
            int v = ebuf[base + idx];
            int s = v & 0xFFFFF;
            int l = v >> 20;
            int r = atomicAdd(&lcsr[l], 1);
            csr[base + st[l] + r] = s;
        }
    }
}

// ---------------- dense matmul: out[i, 0..15] = in[i, :] @ W ----------------

template <int FI>
__global__ void k_matmul(const float* __restrict__ in, const float* __restrict__ W,
                         float* __restrict__ out, int n) {
    __shared__ float sW[FI * H];
    for (int t = threadIdx.x; t < FI * H; t += blockDim.x) sW[t] = W[t];
    __syncthreads();
    int i = blockIdx.x * blockDim.x + threadIdx.x;
    if (i >= n) return;
    float xin[FI];
#pragma unroll
    for (int j = 0; j < FI; j++) xin[j] = in[i * FI + j];
#pragma unroll
    for (int o = 0; o < H; o++) {
        float acc = 0.0f;
#pragma unroll
        for (int j = 0; j < FI; j++) acc += xin[j] * sW[j * H + o];
        out[i * H + o] = acc;
    }
}

// ---------------- CSR gather: fused self-loop + bias + relu (+ pool) ----------------
// 16 threads per node, lane k owns feature k; 2-way edge unroll for MLP.
template <bool POOL>
__global__ void k_gather(const float* __restrict__ tmp, const float* __restrict__ dinv,
                         const int* __restrict__ csr, const int* __restrict__ cursor,
                         const float* __restrict__ bias, float* __restrict__ out,
                         const int* __restrict__ batch, float* __restrict__ g, int n) {
    int i = blockIdx.x * 16 + (threadIdx.x >> 4);
    int k = threadIdx.x & 15;
    if (i >= n) return;
    float di = dinv[i];
    float acc = bias[k] + di * di * tmp[i * H + k];
    float acc2 = 0.0f;
    int j = (i == 0) ? 0 : cursor[i - 1];
    int end = cursor[i];
    for (; j + 2 <= end; j += 2) {
        int s0 = csr[j];
        int s1 = csr[j + 1];
        float w0 = di * dinv[s0];
        float w1 = di * dinv[s1];
        acc  = fmaf(w0, tmp[s0 * H + k], acc);
        acc2 = fmaf(w1, tmp[s1 * H + k], acc2);
    }
    if (j < end) {
        int s = csr[j];
        acc = fmaf(di * dinv[s], tmp[s * H + k], acc);
    }
    float v = fmaxf(acc + acc2, 0.0f);
    if (POOL) {
        atomicAdd(&g[batch[i] * H + k], v);
    } else {
        out[i * H + k] = v;
    }
}

// ---------------- final MLP ----------------

__global__ void k_mlp(const float* __restrict__ g, const float* __restrict__ y,
                      const float* __restrict__ fcW1, const float* __restrict__ fcb1,
                      const float* __restrict__ fcW2, const float* __restrict__ fcb2,
                      const float* __restrict__ fcW3, const float* __restrict__ fcb3,
                      float* __restrict__ out, int ngraph) {
    int i = blockIdx.x * blockDim.x + threadIdx.x;
    if (i >= ngraph) return;
    float in[H + 4];
#pragma unroll
    for (int k = 0; k < H; k++) in[k] = g[i * H + k];
#pragma unroll
    for (int k = 0; k < 4; k++) in[H + k] = y[i * 4 + k];
    float z1[H];
#pragma unroll
    for (int o = 0; o < H; o++) {
        float a = fcb1[o];
#pragma unroll
        for (int j = 0; j < H + 4; j++) a += in[j] * fcW1[j * H + o];
        z1[o] = fmaxf(a, 0.0f);
    }
    float z2[H];
#pragma unroll
    for (int o = 0; o < H; o++) {
        float a = fcb2[o];
#pragma unroll
        for (int j = 0; j < H; j++) a += z1[j] * fcW2[j * H + o];
        z2[o] = fmaxf(a, 0.0f);
    }
    float a = fcb3[0];
#pragma unroll
    for (int j = 0; j < H; j++) a += z2[j] * fcW3[j];
    out[i] = a;
}

// ---------------- fallback (round-2) build kernels ----------------

__global__ void k_deg(const int* __restrict__ dst, int* __restrict__ deg, int e) {
    int i = blockIdx.x * blockDim.x + threadIdx.x;
    if (i < e) atomicAdd(&deg[dst[i]], 1);
}

__global__ void k_dinv(const int* __restrict__ deg, float* __restrict__ dinv, int n) {
    int i = blockIdx.x * blockDim.x + threadIdx.x;
    if (i < n) dinv[i] = rsqrtf((float)deg[i] + 1.0f);
}

__global__ void k_scanA(const int* __restrict__ deg, int* __restrict__ cursor,
                        int* __restrict__ sums, int n) {
    __shared__ int sh[SCAN_CHUNK];
    int t = threadIdx.x;
    int i = blockIdx.x * SCAN_CHUNK + t;
    int v = (i < n) ? deg[i] : 0;
    sh[t] = v;
    __syncthreads();
    for (int off = 1; off < SCAN_CHUNK; off <<= 1) {
        int x = (t >= off) ? sh[t - off] : 0;
        __syncthreads();
        sh[t] += x;
        __syncthreads();
    }
    if (i < n) cursor[i] = sh[t] - v;
    if (t == SCAN_CHUNK - 1) sums[blockIdx.x] = sh[t];
}

__global__ void k_scanB(int* __restrict__ sums, int nb) {
    __shared__ int sh[128];
    int t = threadIdx.x;
    int v = (t < nb) ? sums[t] : 0;
    sh[t] = v;
    __syncthreads();
    for (int off = 1; off < 128; off <<= 1) {
        int x = (t >= off) ? sh[t - off] : 0;
        __syncthreads();
        sh[t] += x;
        __syncthreads();
    }
    if (t < nb) sums[t] = sh[t] - v;
}

__global__ void k_scanC(int* __restrict__ cursor, const int* __restrict__ sums, int n) {
    int i = blockIdx.x * blockDim.x + threadIdx.x;
    if (i < n) cursor[i] += sums[i >> 10];
}

__global__ void k_build(const int* __restrict__ src, const int* __restrict__ dst,
                        int* __restrict__ cursor, int* __restrict__ csr, int e) {
    int i = blockIdx.x * blockDim.x + threadIdx.x;
    if (i < e) {
        int d = dst[i];
        int pos = atomicAdd(&cursor[d], 1);
        csr[pos] = src[i];
    }
}

// ---------------- launch ----------------

extern "C" void kernel_launch(void* const* d_in, const int* in_sizes, int n_in,
                              void* d_out, int out_size, void* d_ws, size_t ws_size,
                              hipStream_t stream) {
    const float* x    = (const float*)d_in[0];
    const int*   ei   = (const int*)d_in[1];   // [2, E]: src then dst
    const float* y    = (const float*)d_in[2];
    const int*   bat  = (const int*)d_in[3];
    const float* W1   = (const float*)d_in[4];
    const float* b1   = (const float*)d_in[5];
    const float* W2   = (const float*)d_in[6];
    const float* b2   = (const float*)d_in[7];
    const float* W3   = (const float*)d_in[8];
    const float* b3   = (const float*)d_in[9];
    const float* fcW1 = (const float*)d_in[10];
    const float* fcb1 = (const float*)d_in[11];
    const float* fcW2 = (const float*)d_in[12];
    const float* fcb2 = (const float*)d_in[13];
    const float* fcW3 = (const float*)d_in[14];
    const float* fcb3 = (const float*)d_in[15];
    float* out = (float*)d_out;

    const int* src = ei;
    const int* dst = ei + N_EDGES;

    const int B = 256;
    const int NH = N_NODES * H;
    const int GH = N_GRAPHS * H;
    const int gN  = (N_NODES + B - 1) / B;
    const int gE  = (N_EDGES + B - 1) / B;
    const int gGH = (GH + B - 1) / B;
    const int gGather = (N_NODES + 15) / 16;

    // ---- fast-path workspace layout ----
    char* w = (char*)d_ws;
    size_t off = 0;
    int*   bucketCnt    = (int*)(w + off); off += (size_t)NB * 4;
    int*   bucketBase   = (int*)(w + off); off += (size_t)NB * 4;
    int*   bucketCursor = (int*)(w + off); off += (size_t)NB * 4;
    int*   cursor       = (int*)(w + off); off += (size_t)N_NODES * 4;
    float* dinv         = (float*)(w + off); off += (size_t)N_NODES * 4;
    int*   ebuf         = (int*)(w + off); off += (size_t)N_EDGES * 4;
    int*   csr          = (int*)(w + off); off += (size_t)N_EDGES * 4;
    float* bufA         = (float*)(w + off); off += (size_t)NH * 4;
    float* bufB         = (float*)(w + off); off += (size_t)NH * 4;
    float* g            = (float*)(w + off); off += (size_t)GH * 4;
    size_t need_fast = off;

    if (ws_size >= need_fast) {
        // ---- bucketed CSR build ----
        k_zero_i<<<(NB + B - 1) / B, B, 0, stream>>>(bucketCnt, NB);
        k_hist<<<256, B, 0, stream>>>(dst, bucketCnt, N_EDGES);
        k_scan_buckets<<<1, NB, 0, stream>>>(bucketCnt, bucketBase, bucketCursor);
        k_bucket<<<(N_EDGES + CHUNK - 1) / CHUNK, B, 0, stream>>>(src, dst, bucketCursor,
                                                                  ebuf, N_EDGES);
        k_csrify<<<NB, B, 0, stream>>>(ebuf, bucketBase, bucketCnt, csr, cursor, dinv);

        // ---- layers ----
        k_matmul<F_IN><<<gN, B, 0, stream>>>(x, W1, bufA, N_NODES);
        k_gather<false><<<gGather, B, 0, stream>>>(bufA, dinv, csr, cursor, b1, bufB,
                                                   nullptr, nullptr, N_NODES);
        k_matmul<H><<<gN, B, 0, stream>>>(bufB, W2, bufA, N_NODES);
        k_gather<false><<<gGather, B, 0, stream>>>(bufA, dinv, csr, cursor, b2, bufB,
                                                   nullptr, nullptr, N_NODES);
        k_matmul<H><<<gN, B, 0, stream>>>(bufB, W3, bufA, N_NODES);
        k_zero_f<<<gGH, B, 0, stream>>>(g, GH);
        k_gather<true><<<gGather, B, 0, stream>>>(bufA, dinv, csr, cursor, b3, nullptr,
                                                  bat, g, N_NODES);

        k_mlp<<<(N_GRAPHS + B - 1) / B, B, 0, stream>>>(g, y, fcW1, fcb1, fcW2, fcb2,
                                                        fcW3, fcb3, out, N_GRAPHS);
    } else {
        // ---- fallback: round-2 path ----
        size_t o2 = 0;
        int*   deg2    = (int*)(w + o2);   o2 += (size_t)N_NODES * 4;
        int*   cur2    = (int*)(w + o2);   o2 += (size_t)N_NODES * 4;
        float* dinv2   = (float*)(w + o2); o2 += (size_t)N_NODES * 4;
        int*   sums2   = (int*)(w + o2);   o2 += 128 * 4;
        int*   csr2    = (int*)(w + o2);   o2 += (size_t)N_EDGES * 4;
        float* bufA2   = (float*)(w + o2); o2 += (size_t)NH * 4;
        float* bufB2   = (float*)(w + o2); o2 += (size_t)NH * 4;
        float* g2      = (float*)(w + o2); o2 += (size_t)GH * 4;

        k_zero_i<<<gN, B, 0, stream>>>(deg2, N_NODES);
        k_deg<<<gE, B, 0, stream>>>(dst, deg2, N_EDGES);
        k_dinv<<<gN, B, 0, stream>>>(deg2, dinv2, N_NODES);
        k_scanA<<<N_CHUNKS, SCAN_CHUNK, 0, stream>>>(deg2, cur2, sums2, N_NODES);
        k_scanB<<<1, 128, 0, stream>>>(sums2, N_CHUNKS);
        k_scanC<<<gN, B, 0, stream>>>(cur2, sums2, N_NODES);
        k_build<<<gE, B, 0, stream>>>(src, dst, cur2, csr2, N_EDGES);

        k_matmul<F_IN><<<gN, B, 0, stream>>>(x, W1, bufA2, N_NODES);
        k_gather<false><<<gGather, B, 0, stream>>>(bufA2, dinv2, csr2, cur2, b1, bufB2,
                                                   nullptr, nullptr, N_NODES);
        k_matmul<H><<<gN, B, 0, stream>>>(bufB2, W2, bufA2, N_NODES);
        k_gather<false><<<gGather, B, 0, stream>>>(bufA2, dinv2, csr2, cur2, b2, bufB2,
                                                   nullptr, nullptr, N_NODES);
        k_matmul<H><<<gN, B, 0, stream>>>(bufB2, W3, bufA2, N_NODES);
        k_zero_f<<<gGH, B, 0, stream>>>(g2, GH);
        k_gather<true><<<gGather, B, 0, stream>>>(bufA2, dinv2, csr2, cur2, b3, nullptr,
                                                  bat, g2, N_NODES);
        k_mlp<<<(N_GRAPHS + B - 1) / B, B, 0, stream>>>(g2, y, fcW1, fcb1, fcW2, fcb2,
                                                        fcW3, fcb3, out, N_GRAPHS);
    }
}

// Round 4
// 253.569 us; speedup vs baseline: 3.0562x; 1.3422x over previous
//
#include <hip/hip_runtime.h>
#include <hip/hip_fp16.h>

#define N_NODES 100000
#define N_EDGES 3200000
#define N_GRAPHS 1024
#define F_IN 4
#define H 16

#define NB 1024      // dst buckets
#define NPB 98       // nodes per bucket (98*1021 >= 100000)
#define CAP 4096     // per-bucket LDS fast-path capacity (mean 3125, sigma 56)
#define CHUNK 4096   // edges per block in k_bucket
#define EPT 16       // edges per thread

// ---------------- tiny utility kernels ----------------

__global__ void k_zero_f(float* __restrict__ p, int n) {
    int i = blockIdx.x * blockDim.x + threadIdx.x;
    if (i < n) p[i] = 0.0f;
}

__global__ void k_zero_i(int* __restrict__ p, int n) {
    int i = blockIdx.x * blockDim.x + threadIdx.x;
    if (i < n) p[i] = 0;
}

// ---------------- fast CSR build (bucketed) ----------------

__global__ void k_hist(const int* __restrict__ dst, int* __restrict__ bucketCnt, int e) {
    __shared__ int h[NB];
    for (int t = threadIdx.x; t < NB; t += blockDim.x) h[t] = 0;
    __syncthreads();
    for (int i = blockIdx.x * blockDim.x + threadIdx.x; i < e; i += gridDim.x * blockDim.x)
        atomicAdd(&h[dst[i] / NPB], 1);
    __syncthreads();
    for (int t = threadIdx.x; t < NB; t += blockDim.x) {
        int c = h[t];
        if (c) atomicAdd(&bucketCnt[t], c);
    }
}

__global__ void k_scan_buckets(const int* __restrict__ bucketCnt,
                               int* __restrict__ bucketBase,
                               int* __restrict__ bucketCursor) {
    __shared__ int sh[NB];
    int t = threadIdx.x;
    int v = bucketCnt[t];
    sh[t] = v;
    __syncthreads();
    for (int off = 1; off < NB; off <<= 1) {
        int x = (t >= off) ? sh[t - off] : 0;
        __syncthreads();
        sh[t] += x;
        __syncthreads();
    }
    int base = sh[t] - v;
    bucketBase[t] = base;
    bucketCursor[t] = base;
}

// payload packed: (local_dst << 20) | src
__global__ void k_bucket(const int* __restrict__ src, const int* __restrict__ dst,
                         int* __restrict__ bucketCursor, int* __restrict__ ebuf, int e) {
    __shared__ int cnt[NB];
    __shared__ int lbase[NB];
    int t = threadIdx.x;
    for (int q = t; q < NB; q += blockDim.x) cnt[q] = 0;
    __syncthreads();
    int e0 = blockIdx.x * CHUNK;
    int vq[EPT], bq[EPT], rq[EPT];
#pragma unroll
    for (int q = 0; q < EPT; ++q) {
        int ei = e0 + t + q * 256;
        bq[q] = -1;
        if (ei < e) {
            int s = src[ei];
            int d = dst[ei];
            int b = d / NPB;
            int l = d - b * NPB;
            vq[q] = s | (l << 20);
            bq[q] = b;
            rq[q] = atomicAdd(&cnt[b], 1);
        }
    }
    __syncthreads();
    for (int q = t; q < NB; q += blockDim.x) {
        int c = cnt[q];
        lbase[q] = c ? atomicAdd(&bucketCursor[q], c) : 0;
    }
    __syncthreads();
#pragma unroll
    for (int q = 0; q < EPT; ++q)
        if (bq[q] >= 0) ebuf[lbase[bq[q]] + rq[q]] = vq[q];
}

// one block per bucket: group by node, emit coalesced CSR + cursor + dinv
__global__ void k_csrify(const int* __restrict__ ebuf, const int* __restrict__ bucketBase,
                         const int* __restrict__ bucketCnt, int* __restrict__ csr,
                         int* __restrict__ cursor, float* __restrict__ dinv) {
    __shared__ int cnt[128];
    __shared__ int sc[128];
    __shared__ int st[128];
    __shared__ int lcsr[CAP];
    int t = threadIdx.x;
    int b = blockIdx.x;
    int base = bucketBase[b];
    int m = bucketCnt[b];
    int nbase = b * NPB;
    if (t < 128) cnt[t] = 0;
    __syncthreads();

    if (m <= CAP) {
        int vs[EPT], ls[EPT], rk[EPT];
#pragma unroll
        for (int q = 0; q < EPT; ++q) {
            int idx = t + q * 256;
            if (idx < m) {
                int v = ebuf[base + idx];
                int s = v & 0xFFFFF;
                int l = v >> 20;
                vs[q] = s;
                ls[q] = l;
                rk[q] = atomicAdd(&cnt[l], 1);
            }
        }
        __syncthreads();
        int v0 = (t < 128) ? cnt[t] : 0;
        if (t < 128) sc[t] = v0;
        __syncthreads();
        for (int off = 1; off < 128; off <<= 1) {
            int x = (t < 128 && t >= off) ? sc[t - off] : 0;
            __syncthreads();
            if (t < 128) sc[t] += x;
            __syncthreads();
        }
        if (t < 128) st[t] = sc[t] - v0;
        __syncthreads();
        if (t < NPB) {
            int i = nbase + t;
            if (i < N_NODES) {
                dinv[i] = rsqrtf((float)cnt[t] + 1.0f);
                cursor[i] = base + st[t] + cnt[t];
            }
        }
#pragma unroll
        for (int q = 0; q < EPT; ++q) {
            int idx = t + q * 256;
            if (idx < m) lcsr[st[ls[q]] + rk[q]] = vs[q];
        }
        __syncthreads();
        for (int idx = t; idx < m; idx += 256) csr[base + idx] = lcsr[idx];
    } else {
        // capacity-proof slow path
        for (int idx = t; idx < m; idx += 256) {
            int v = ebuf[base + idx];
            atomicAdd(&cnt[v >> 20], 1);
        }
        __syncthreads();
        int v0 = (t < 128) ? cnt[t] : 0;
        if (t < 128) sc[t] = v0;
        __syncthreads();
        for (int off = 1; off < 128; off <<= 1) {
            int x = (t < 128 && t >= off) ? sc[t - off] : 0;
            __syncthreads();
            if (t < 128) sc[t] += x;
            __syncthreads();
        }
        if (t < 128) st[t] = sc[t] - v0;
        if (t < 128) lcsr[t] = 0;  // reuse as cnt2
        __syncthreads();
        if (t < NPB) {
            int i = nbase + t;
            if (i < N_NODES) {
                dinv[i] = rsqrtf((float)cnt[t] + 1.0f);
                cursor[i] = base + st[t] + cnt[t];
            }
        }
        for (int idx = t; idx < m; idx += 256) {
            int v = ebuf[base + idx];
            int s = v & 0xFFFFF;
            int l = v >> 20;
            int r = atomicAdd(&lcsr[l], 1);
            csr[base + st[l] + r] = s;
        }
    }
}

// ---------------- prescale: ts0 = half(dinv[i] * x[i,k]) ----------------

__global__ void k_prescale(const float* __restrict__ x, const float* __restrict__ dinv,
                           __half* __restrict__ ts, int n4) {
    int t = blockIdx.x * blockDim.x + threadIdx.x;
    if (t < n4) ts[t] = __float2half(dinv[t >> 2] * x[t]);
}

// ---------------- CSR gather over pre-scaled fp16 features ----------------
// F lanes per node; agg[i,k] = dinv[i] * (ts[i,k] + sum_{s in N(i)} ts[s,k])
template <int F>
__global__ void k_gather(const __half* __restrict__ ts, const float* __restrict__ dinv,
                         const int* __restrict__ csr, const int* __restrict__ cursor,
                         float* __restrict__ agg, int n) {
    int i = blockIdx.x * (256 / F) + threadIdx.x / F;
    int k = threadIdx.x % F;
    if (i >= n) return;
    float a0 = __half2float(ts[i * F + k]);   // self-loop term
    float a1 = 0.0f, a2 = 0.0f, a3 = 0.0f;
    int j = (i == 0) ? 0 : cursor[i - 1];
    int end = cursor[i];
    for (; j + 4 <= end; j += 4) {
        int s0 = csr[j];
        int s1 = csr[j + 1];
        int s2 = csr[j + 2];
        int s3 = csr[j + 3];
        a0 += __half2float(ts[s0 * F + k]);
        a1 += __half2float(ts[s1 * F + k]);
        a2 += __half2float(ts[s2 * F + k]);
        a3 += __half2float(ts[s3 * F + k]);
    }
    for (; j < end; ++j) a0 += __half2float(ts[csr[j] * F + k]);
    agg[i * F + k] = dinv[i] * ((a0 + a1) + (a2 + a3));
}

// ---------------- per-node transform: h = relu(agg @ W + b) ----------------
// 16 lanes per node (lane = output feature). Non-pool: write ts_out = half(dinv*h).
// Pool: atomicAdd into g[batch[i]].
template <int FI, bool POOL>
__global__ void k_transform(const float* __restrict__ agg, const float* __restrict__ W,
                            const float* __restrict__ bias, const float* __restrict__ dinv,
                            __half* __restrict__ ts_out, const int* __restrict__ batch,
                            float* __restrict__ g, int n) {
    __shared__ float sW[FI * H];
    for (int t = threadIdx.x; t < FI * H; t += blockDim.x) sW[t] = W[t];
    __syncthreads();
    int i = blockIdx.x * 16 + (threadIdx.x >> 4);
    int k = threadIdx.x & 15;
    if (i >= n) return;
    float acc = bias[k];
#pragma unroll
    for (int j = 0; j < FI; j++) acc = fmaf(agg[i * FI + j], sW[j * H + k], acc);
    float h = fmaxf(acc, 0.0f);
    if (POOL) {
        atomicAdd(&g[batch[i] * H + k], h);
    } else {
        ts_out[i * H + k] = __float2half(dinv[i] * h);
    }
}

// ---------------- final MLP ----------------

__global__ void k_mlp(const float* __restrict__ g, const float* __restrict__ y,
                      const float* __restrict__ fcW1, const float* __restrict__ fcb1,
                      const float* __restrict__ fcW2, const float* __restrict__ fcb2,
                      const float* __restrict__ fcW3, const float* __restrict__ fcb3,
                      float* __restrict__ out, int ngraph) {
    int i = blockIdx.x * blockDim.x + threadIdx.x;
    if (i >= ngraph) return;
    float in[H + 4];
#pragma unroll
    for (int k = 0; k < H; k++) in[k] = g[i * H + k];
#pragma unroll
    for (int k = 0; k < 4; k++) in[H + k] = y[i * 4 + k];
    float z1[H];
#pragma unroll
    for (int o = 0; o < H; o++) {
        float a = fcb1[o];
#pragma unroll
        for (int j = 0; j < H + 4; j++) a += in[j] * fcW1[j * H + o];
        z1[o] = fmaxf(a, 0.0f);
    }
    float z2[H];
#pragma unroll
    for (int o = 0; o < H; o++) {
        float a = fcb2[o];
#pragma unroll
        for (int j = 0; j < H; j++) a += z1[j] * fcW2[j * H + o];
        z2[o] = fmaxf(a, 0.0f);
    }
    float a = fcb3[0];
#pragma unroll
    for (int j = 0; j < H; j++) a += z2[j] * fcW3[j];
    out[i] = a;
}

// ---------------- launch ----------------

extern "C" void kernel_launch(void* const* d_in, const int* in_sizes, int n_in,
                              void* d_out, int out_size, void* d_ws, size_t ws_size,
                              hipStream_t stream) {
    const float* x    = (const float*)d_in[0];
    const int*   ei   = (const int*)d_in[1];   // [2, E]: src then dst
    const float* y    = (const float*)d_in[2];
    const int*   bat  = (const int*)d_in[3];
    const float* W1   = (const float*)d_in[4];
    const float* b1   = (const float*)d_in[5];
    const float* W2   = (const float*)d_in[6];
    const float* b2   = (const float*)d_in[7];
    const float* W3   = (const float*)d_in[8];
    const float* b3   = (const float*)d_in[9];
    const float* fcW1 = (const float*)d_in[10];
    const float* fcb1 = (const float*)d_in[11];
    const float* fcW2 = (const float*)d_in[12];
    const float* fcb2 = (const float*)d_in[13];
    const float* fcW3 = (const float*)d_in[14];
    const float* fcb3 = (const float*)d_in[15];
    float* out = (float*)d_out;

    const int* src = ei;
    const int* dst = ei + N_EDGES;

    const int B = 256;
    const int GH = N_GRAPHS * H;
    const int gGH = (GH + B - 1) / B;
    const int gNode16 = (N_NODES + 15) / 16;   // 16 lanes/node kernels
    const int gNode64 = (N_NODES + 63) / 64;   // 4 lanes/node gather
    const int N4 = N_NODES * F_IN;

    // ---- workspace layout ----
    char* w = (char*)d_ws;
    size_t off = 0;
    int*    bucketCnt    = (int*)(w + off);    off += (size_t)NB * 4;
    int*    bucketBase   = (int*)(w + off);    off += (size_t)NB * 4;
    int*    bucketCursor = (int*)(w + off);    off += (size_t)NB * 4;
    int*    cursor       = (int*)(w + off);    off += (size_t)N_NODES * 4;
    float*  dinv         = (float*)(w + off);  off += (size_t)N_NODES * 4;
    int*    ebuf         = (int*)(w + off);    off += (size_t)N_EDGES * 4;
    int*    csr          = (int*)(w + off);    off += (size_t)N_EDGES * 4;
    __half* ts0          = (__half*)(w + off); off += (size_t)N4 * 2;
    __half* ts1          = (__half*)(w + off); off += (size_t)N_NODES * H * 2;
    __half* ts2          = (__half*)(w + off); off += (size_t)N_NODES * H * 2;
    float*  agg          = (float*)(w + off);  off += (size_t)N_NODES * H * 4;
    float*  g            = (float*)(w + off);  off += (size_t)GH * 4;
    (void)ws_size;

    // ---- bucketed CSR build ----
    k_zero_i<<<(NB + B - 1) / B, B, 0, stream>>>(bucketCnt, NB);
    k_hist<<<256, B, 0, stream>>>(dst, bucketCnt, N_EDGES);
    k_scan_buckets<<<1, NB, 0, stream>>>(bucketCnt, bucketBase, bucketCursor);
    k_bucket<<<(N_EDGES + CHUNK - 1) / CHUNK, B, 0, stream>>>(src, dst, bucketCursor,
                                                              ebuf, N_EDGES);
    k_csrify<<<NB, B, 0, stream>>>(ebuf, bucketBase, bucketCnt, csr, cursor, dinv);

    // ---- layer 1: gather raw x (4 features), then transform 4->16 ----
    k_prescale<<<(N4 + B - 1) / B, B, 0, stream>>>(x, dinv, ts0, N4);
    k_gather<F_IN><<<gNode64, B, 0, stream>>>(ts0, dinv, csr, cursor, agg, N_NODES);
    k_transform<F_IN, false><<<gNode16, B, 0, stream>>>(agg, W1, b1, dinv, ts1,
                                                        nullptr, nullptr, N_NODES);
    // ---- layer 2 ----
    k_gather<H><<<gNode16, B, 0, stream>>>(ts1, dinv, csr, cursor, agg, N_NODES);
    k_transform<H, false><<<gNode16, B, 0, stream>>>(agg, W2, b2, dinv, ts2,
                                                     nullptr, nullptr, N_NODES);
    // ---- layer 3 + fused pool ----
    k_gather<H><<<gNode16, B, 0, stream>>>(ts2, dinv, csr, cursor, agg, N_NODES);
    k_zero_f<<<gGH, B, 0, stream>>>(g, GH);
    k_transform<H, true><<<gNode16, B, 0, stream>>>(agg, W3, b3, dinv, nullptr,
                                                    bat, g, N_NODES);

    // ---- final MLP ----
    k_mlp<<<(N_GRAPHS + B - 1) / B, B, 0, stream>>>(g, y, fcW1, fcb1, fcW2, fcb2,
                                                    fcW3, fcb3, out, N_GRAPHS);
}